// Round 2
// baseline (5442.170 us; speedup 1.0000x reference)
//
#include <hip/hip_runtime.h>
#include <stdint.h>

// Problem constants (from reference)
#define B_N 2048
#define T_N 100
#define H_N 256
#define L_N 128
#define NV_N 5
#define COLS (H_N + 2 * L_N)   // 512 columns of all_hidden_states

// Output element offsets, concatenated in return order:
// new_h [B,H], all_hidden_states [B,T,512], seg_rep [B,H]
static constexpr long long OUT_ALLH = (long long)B_N * H_N;                     // 524288
static constexpr long long OUT_SEG  = OUT_ALLH + (long long)B_N * T_N * COLS;   // 105381888

__device__ __forceinline__ float bits2f(uint32_t u) {
    union { uint32_t u; float f; } v; v.u = u; return v.f;
}
__device__ __forceinline__ uint16_t f2bf(float f) {
    union { float f; uint32_t u; } v; v.f = f;
    uint32_t r = (v.u + 0x7FFFu + ((v.u >> 16) & 1u)) >> 16;   // round-nearest-even
    return (uint16_t)r;
}

// ---------------------------------------------------------------------------
// Runtime dtype detection: reads 64 uint32 words of W_cs. If stored fp32,
// values ~0.05*N(0,1) have exponent field in [97,130]. If stored bf16, the
// fp32-exponent field aliases the high-bf16's low-exponent+mantissa bits,
// landing ~[226,253]. Majority vote => is_fp32.
// ---------------------------------------------------------------------------
__device__ __forceinline__ int detect_f32(const uint32_t* __restrict__ w) {
    int cnt = 0;
    #pragma unroll 8
    for (int i = 0; i < 64; ++i) {
        uint32_t e = (w[i] >> 23) & 0xFFu;
        cnt += (e >= 97u && e <= 130u) ? 1 : 0;
    }
    return cnt >= 32 ? 1 : 0;
}

// ---------------------------------------------------------------------------
// Dtype-abstracted element access. Index units are ELEMENTS.
// ---------------------------------------------------------------------------
template <bool F32> struct IO;

template <> struct IO<true> {
    static __device__ __forceinline__ void ld4(const void* p, long long idx, float f[4]) {
        const float4 v = *(const float4*)((const float*)p + idx);
        f[0] = v.x; f[1] = v.y; f[2] = v.z; f[3] = v.w;
    }
    static __device__ __forceinline__ float ld1(const void* p, long long idx) {
        return ((const float*)p)[idx];
    }
    static __device__ __forceinline__ void st4(void* p, long long idx, const float f[4]) {
        *(float4*)((float*)p + idx) = make_float4(f[0], f[1], f[2], f[3]);
    }
    static __device__ __forceinline__ void st4z(void* p, long long idx) {
        *(float4*)((float*)p + idx) = make_float4(0.f, 0.f, 0.f, 0.f);
    }
};

template <> struct IO<false> {
    static __device__ __forceinline__ void ld4(const void* p, long long idx, float f[4]) {
        uint2 u = *(const uint2*)((const uint16_t*)p + idx);
        f[0] = bits2f(u.x << 16);
        f[1] = bits2f(u.x & 0xFFFF0000u);
        f[2] = bits2f(u.y << 16);
        f[3] = bits2f(u.y & 0xFFFF0000u);
    }
    static __device__ __forceinline__ float ld1(const void* p, long long idx) {
        return bits2f(((uint32_t)((const uint16_t*)p)[idx]) << 16);
    }
    static __device__ __forceinline__ void st4(void* p, long long idx, const float f[4]) {
        uint2 u;
        u.x = (uint32_t)f2bf(f[0]) | ((uint32_t)f2bf(f[1]) << 16);
        u.y = (uint32_t)f2bf(f[2]) | ((uint32_t)f2bf(f[3]) << 16);
        *(uint2*)((uint16_t*)p + idx) = u;
    }
    static __device__ __forceinline__ void st4z(void* p, long long idx) {
        *(uint2*)((uint16_t*)p + idx) = make_uint2(0u, 0u);
    }
};

__device__ __forceinline__ float sigmoid_f(float x) {
    x = fminf(fmaxf(x, -30.f), 30.f);
    return 1.f / (1.f + __expf(-x));
}
__device__ __forceinline__ float tanh_f(float x) {
    x = fminf(fmaxf(x, -15.f), 15.f);
    float e = __expf(-2.f * x);
    return (1.f - e) / (1.f + e);
}

// ---------------------------------------------------------------------------
// Kernel 1: fill all_hidden_states[:, :, 256:512] with masked tree/graph
// broadcast (zeros at t >= len). 64 threads per (b,t), 4 elements per thread.
// ---------------------------------------------------------------------------
template <bool F32>
__global__ __launch_bounds__(256) void latent_fill_kernel(
    const void* __restrict__ tree,
    const void* __restrict__ graph,
    const int* __restrict__ lengths,
    const void* __restrict__ Wcs_detect,
    void* __restrict__ out)
{
    __shared__ int s_is32;
    if (threadIdx.x == 0) s_is32 = detect_f32((const uint32_t*)Wcs_detect);
    __syncthreads();
    if ((s_is32 != 0) != F32) return;

    long long idx = (long long)blockIdx.x * 256 + threadIdx.x;   // 0 .. B*T*64
    int c = ((int)(idx & 63)) * 4;           // 0..252 within latent cols
    long long bt = idx >> 6;                 // b*T + t
    int t = (int)(bt % T_N);
    int b = (int)(bt / T_N);

    long long dst = OUT_ALLH + bt * COLS + H_N + c;
    if (t < lengths[b]) {
        float v[4];
        if (c < L_N) IO<F32>::ld4(tree, (long long)b * L_N + c, v);
        else         IO<F32>::ld4(graph, (long long)b * L_N + (c - L_N), v);
        IO<F32>::st4(out, dst, v);
    } else {
        IO<F32>::st4z(out, dst);
    }
}

// ---------------------------------------------------------------------------
// Kernel 2: persistent GRU. One wave (64 lanes) per batch row; lane owns
// columns n0..n0+3. h kept in fp32 registers + fp32 copy in wave-private LDS
// for the k-dim broadcast (wave64 lockstep; DS ops in-order within a wave).
// ---------------------------------------------------------------------------
template <bool F32>
__global__ __launch_bounds__(256, 2) void gru_kernel(
    const void* __restrict__ x_seq,
    const void* __restrict__ hidden,
    const void* __restrict__ graph,
    const int* __restrict__ lengths,
    const void* __restrict__ Wcs, const void* __restrict__ bcs,
    const void* __restrict__ Wz,  const void* __restrict__ bz,
    const void* __restrict__ Wr,  const void* __restrict__ br,
    const void* __restrict__ Wh,  const void* __restrict__ bh,
    void* __restrict__ out)
{
    __shared__ int s_is32;
    __shared__ float sh[4][2][H_N];          // per wave: [0]=h (fp32), [1]=r*h
    if (threadIdx.x == 0) s_is32 = detect_f32((const uint32_t*)Wcs);
    __syncthreads();
    if ((s_is32 != 0) != F32) return;

    const int wave = threadIdx.x >> 6;
    const int lane = threadIdx.x & 63;
    const int b = blockIdx.x * 4 + wave;
    const int n0 = lane * 4;
    float* hS  = sh[wave][0];
    float* rhS = sh[wave][1];
    const int len = lengths[b];

    float bzv[4], brv[4], bhv[4];
    IO<F32>::ld4(bz, n0, bzv);
    IO<F32>::ld4(br, n0, brv);
    IO<F32>::ld4(bh, n0, bhv);

    // ---- h0 = relu(concat([hidden, graph]) @ Wcs + bcs) ----
    float h[4];
    {
        float acc[4];
        IO<F32>::ld4(bcs, n0, acc);
        #pragma unroll 4
        for (int k = 0; k < H_N; ++k) {
            float xv = IO<F32>::ld1(hidden, (long long)b * H_N + k);
            float w[4]; IO<F32>::ld4(Wcs, (long long)k * H_N + n0, w);
            acc[0] += xv * w[0]; acc[1] += xv * w[1];
            acc[2] += xv * w[2]; acc[3] += xv * w[3];
        }
        #pragma unroll 4
        for (int k = 0; k < L_N; ++k) {
            float xv = IO<F32>::ld1(graph, (long long)b * L_N + k);
            float w[4]; IO<F32>::ld4(Wcs, (long long)(H_N + k) * H_N + n0, w);
            acc[0] += xv * w[0]; acc[1] += xv * w[1];
            acc[2] += xv * w[2]; acc[3] += xv * w[3];
        }
        #pragma unroll
        for (int j = 0; j < 4; ++j) h[j] = fmaxf(acc[j], 0.f);
    }
    #pragma unroll
    for (int j = 0; j < 4; ++j) hS[n0 + j] = h[j];

    float smax[4] = {-1e30f, -1e30f, -1e30f, -1e30f};

    for (int t = 0; t < len; ++t) {
        float xt[NV_N];
        #pragma unroll
        for (int i = 0; i < NV_N; ++i)
            xt[i] = IO<F32>::ld1(x_seq, ((long long)b * T_N + t) * NV_N + i);

        float az[4] = {bzv[0], bzv[1], bzv[2], bzv[3]};
        float ar[4] = {brv[0], brv[1], brv[2], brv[3]};

        // x-part rows 0..4
        #pragma unroll
        for (int kk = 0; kk < NV_N; ++kk) {
            float wz4[4], wr4[4];
            IO<F32>::ld4(Wz, (long long)kk * H_N + n0, wz4);
            IO<F32>::ld4(Wr, (long long)kk * H_N + n0, wr4);
            #pragma unroll
            for (int j = 0; j < 4; ++j) {
                az[j] += xt[kk] * wz4[j];
                ar[j] += xt[kk] * wr4[j];
            }
        }
        // h-part rows 5..260, broadcast fp32 h from LDS
        #pragma unroll 4
        for (int k = 0; k < H_N; ++k) {
            float xv = hS[k];
            float wz4[4], wr4[4];
            IO<F32>::ld4(Wz, (long long)(NV_N + k) * H_N + n0, wz4);
            IO<F32>::ld4(Wr, (long long)(NV_N + k) * H_N + n0, wr4);
            #pragma unroll
            for (int j = 0; j < 4; ++j) {
                az[j] += xv * wz4[j];
                ar[j] += xv * wr4[j];
            }
        }
        float z[4], r[4];
        #pragma unroll
        for (int j = 0; j < 4; ++j) {
            z[j] = sigmoid_f(az[j]);
            r[j] = sigmoid_f(ar[j]);
        }
        #pragma unroll
        for (int j = 0; j < 4; ++j) rhS[n0 + j] = r[j] * h[j];

        float ag[4] = {bhv[0], bhv[1], bhv[2], bhv[3]};
        #pragma unroll
        for (int kk = 0; kk < NV_N; ++kk) {
            float wh4[4];
            IO<F32>::ld4(Wh, (long long)kk * H_N + n0, wh4);
            #pragma unroll
            for (int j = 0; j < 4; ++j) ag[j] += xt[kk] * wh4[j];
        }
        #pragma unroll 4
        for (int k = 0; k < H_N; ++k) {
            float xv = rhS[k];
            float wh4[4];
            IO<F32>::ld4(Wh, (long long)(NV_N + k) * H_N + n0, wh4);
            #pragma unroll
            for (int j = 0; j < 4; ++j) ag[j] += xv * wh4[j];
        }
        #pragma unroll
        for (int j = 0; j < 4; ++j) {
            float pre = tanh_f(ag[j]);
            h[j] = (1.f - z[j]) * h[j] + z[j] * pre;
            hS[n0 + j] = h[j];
            smax[j] = fmaxf(smax[j], h[j]);
        }

        IO<F32>::st4(out, OUT_ALLH + ((long long)b * T_N + t) * COLS + n0, h);
        if (t == len - 1)
            IO<F32>::st4(out, (long long)b * H_N + n0, h);
    }

    // zero-fill invalid timesteps of all_h columns (harness poisons d_out)
    for (int t = len; t < T_N; ++t)
        IO<F32>::st4z(out, OUT_ALLH + ((long long)b * T_N + t) * COLS + n0);

    // seg_rep
    IO<F32>::st4(out, OUT_SEG + (long long)b * H_N + n0, smax);
}

extern "C" void kernel_launch(void* const* d_in, const int* in_sizes, int n_in,
                              void* d_out, int out_size, void* d_ws, size_t ws_size,
                              hipStream_t stream) {
    const void* x_seq  = d_in[0];
    const void* hidden = d_in[1];
    const void* tree   = d_in[2];
    const void* graph  = d_in[3];
    const int*  lens   = (const int*)d_in[4];
    const void* Wcs    = d_in[5];
    const void* bcs    = d_in[6];
    const void* Wz     = d_in[7];
    const void* bz     = d_in[8];
    const void* Wr     = d_in[9];
    const void* br     = d_in[10];
    const void* Wh     = d_in[11];
    const void* bh     = d_in[12];
    void* out = d_out;

    long long work = (long long)B_N * T_N * 64;
    int blocks = (int)(work / 256);   // 51200

    // Launch BOTH dtype variants; each block self-selects via detect_f32 and
    // the mismatching variant exits after ~64 cached loads. Deterministic
    // work per call => graph-capture safe.
    hipLaunchKernelGGL((latent_fill_kernel<true>),  dim3(blocks), dim3(256), 0, stream,
                       tree, graph, lens, Wcs, out);
    hipLaunchKernelGGL((latent_fill_kernel<false>), dim3(blocks), dim3(256), 0, stream,
                       tree, graph, lens, Wcs, out);

    hipLaunchKernelGGL((gru_kernel<true>), dim3(B_N / 4), dim3(256), 0, stream,
                       x_seq, hidden, graph, lens,
                       Wcs, bcs, Wz, bz, Wr, br, Wh, bh, out);
    hipLaunchKernelGGL((gru_kernel<false>), dim3(B_N / 4), dim3(256), 0, stream,
                       x_seq, hidden, graph, lens,
                       Wcs, bcs, Wz, bz, Wr, br, Wh, bh, out);
}